// Round 7
// baseline (274.443 us; speedup 1.0000x reference)
//
#include <hip/hip_runtime.h>
#include <hip/hip_bf16.h>
#include <math.h>

// Fused GNN readout via bf16-split MFMA (v_mfma_f32_32x32x16_bf16):
//   feat1 = relu(concat(h,x) @ W1 + b1)   [N,256]  GEMM1: K=400 (25 k-steps), A=bf16 hi, B=hi+lo
//   feat2 = relu(feat1 @ W2 + b2)         [N,64]   GEMM2: K=256, A=bf16 hi, B=hi+lo
//   s_n   = feat2 . Wout ; out = sigmoid(segment_sum(s_n) + bout)
// R7: BARRIER-FREE GEMM1 — no LDS staging for A at all. Each wave loads its A
//     fragments directly from global (block working set 100KB => L2-resident
//     reuse; first touch is the inevitable 320MB HBM read). 1-deep register
//     prefetch of A(fp32)+B(bf16); full unroll; vmcnt never force-drained.

typedef __attribute__((ext_vector_type(8)))  short short8v;
typedef __attribute__((ext_vector_type(16))) float f32x16;

#define G_NUM 2048
#define HID 200
#define EMB 200
#define DIN 400
#define NH1 256
#define NH2 64
#define BM  64
#define NKS1 25        // bf16 K-steps (of 16) for GEMM1: 400 = 25*16 exactly
#define NKS2 16        // K-steps for GEMM2 (K=256)

#define W1P_SH8 (NKS1*8*64)   // 12800 fragments (16B each) per plane
#define W2P_SH8 (NKS2*2*64)   // 2048

__device__ __forceinline__ unsigned short f2bf(float f) {
    union { float f; unsigned u; } v; v.f = f;
    unsigned r = v.u + 0x7fffu + ((v.u >> 16) & 1u);   // RNE
    return (unsigned short)(r >> 16);
}
__device__ __forceinline__ float bf2f(unsigned short b) {
    union { unsigned u; float f; } v; v.u = ((unsigned)b) << 16;
    return v.f;
}
// 8 fp32 -> 8 bf16 (RNE) via packed converts
__device__ __forceinline__ short8v cvt8(float4 a, float4 b) {
    union { __hip_bfloat162 q[4]; short8v s8; } u;
    u.q[0] = __float22bfloat162_rn(make_float2(a.x, a.y));
    u.q[1] = __float22bfloat162_rn(make_float2(a.z, a.w));
    u.q[2] = __float22bfloat162_rn(make_float2(b.x, b.y));
    u.q[3] = __float22bfloat162_rn(make_float2(b.z, b.w));
    return u.s8;
}

// Pre-pack W1/W2 into MFMA-fragment order, hi/lo bf16 planes.
// Fragment (ks, ntile, lane) holds 8 bf16: B[k0+j][col], k0=ks*16+(lane>>5)*8,
// col=ntile*32+(lane&31). Contiguous-8 k in BOTH A and B => any consistent
// hw k-permutation cancels in the dot product.
__global__ void pack_weights(const float* __restrict__ W1, const float* __restrict__ W2,
                             unsigned short* __restrict__ w1h, unsigned short* __restrict__ w1l,
                             unsigned short* __restrict__ w2h, unsigned short* __restrict__ w2l)
{
    int idx = blockIdx.x * 256 + threadIdx.x;
    if (idx < W1P_SH8) {
        int l  = idx & 63;
        int nt = (idx >> 6) & 7;
        int ks = idx >> 9;
        int col = nt * 32 + (l & 31);
        int k0  = ks * 16 + (l >> 5) * 8;
        short8v H, L;
        #pragma unroll
        for (int j = 0; j < 8; ++j) {
            float v = W1[(size_t)(k0 + j) * NH1 + col];
            unsigned short hh = f2bf(v);
            H[j] = (short)hh;
            L[j] = (short)f2bf(v - bf2f(hh));
        }
        ((short8v*)w1h)[idx] = H;
        ((short8v*)w1l)[idx] = L;
    } else if (idx < W1P_SH8 + W2P_SH8) {
        int i2 = idx - W1P_SH8;
        int l  = i2 & 63;
        int nt = (i2 >> 6) & 1;
        int ks = i2 >> 7;
        int col = nt * 32 + (l & 31);
        int k0  = ks * 16 + (l >> 5) * 8;
        short8v H, L;
        #pragma unroll
        for (int j = 0; j < 8; ++j) {
            float v = W2[(size_t)(k0 + j) * NH2 + col];
            unsigned short hh = f2bf(v);
            H[j] = (short)hh;
            L[j] = (short)f2bf(v - bf2f(hh));
        }
        ((short8v*)w2h)[i2] = H;
        ((short8v*)w2l)[i2] = L;
    }
}

__launch_bounds__(256, 4)
__global__ void fused_readout(const float* __restrict__ h, const float* __restrict__ x,
                              const int* __restrict__ batch,
                              const unsigned short* __restrict__ w1h, const unsigned short* __restrict__ w1l,
                              const unsigned short* __restrict__ w2h, const unsigned short* __restrict__ w2l,
                              const float* __restrict__ b1, const float* __restrict__ b2,
                              const float* __restrict__ Wout,
                              float* __restrict__ gf1d, int N)
{
    // 32768 B LDS:
    //   [GEMM2] F1h [64][256] bf16 = 32768 B (XOR-8-block swizzled cols)
    //   [pool ] s2p[2][64] f32 at 0, srow[64] f32 at byte 512 (after GEMM2)
    __shared__ __align__(16) char lds[32768];
    unsigned short* F1h = (unsigned short*)lds;
    float* s2p  = (float*)lds;          // 128 floats
    float* srow = (float*)(lds + 512);  // 64 floats

    const int t    = threadIdx.x;
    const int lane = t & 63;
    const int w    = t >> 6;
    const int n0   = blockIdx.x * BM;
    const int l31  = lane & 31;
    const int hs   = lane >> 5;         // k-half select

    const short8v* W1H = (const short8v*)w1h;
    const short8v* W1L = (const short8v*)w1l;

    // per-lane A row pointers (clamped; invalid rows excluded at pooling)
    const int r0 = min(n0 + l31,      N - 1);
    const int r1 = min(n0 + 32 + l31, N - 1);
    const float* __restrict__ h0 = h + (size_t)r0 * HID;
    const float* __restrict__ h1 = h + (size_t)r1 * HID;
    const float* __restrict__ x0 = x + (size_t)r0 * EMB - HID;  // x0+c valid for c>=200
    const float* __restrict__ x1 = x + (size_t)r1 * EMB - HID;

    f32x16 acc00, acc01, acc10, acc11;
    #pragma unroll
    for (int r = 0; r < 16; ++r) { acc00[r] = 0.f; acc01[r] = 0.f; acc10[r] = 0.f; acc11[r] = 0.f; }

    // ---- prologue: load A(ks=0) fp32 + B(ks=0) frags into registers ----
    float4 a00, a01, a10, a11;
    {
        const int c = hs * 8;   // < 200: all h
        a00 = *(const float4*)(h0 + c);  a01 = *(const float4*)(h0 + c + 4);
        a10 = *(const float4*)(h1 + c);  a11 = *(const float4*)(h1 + c + 4);
    }
    short8v cbh0, cbh1, cbl0, cbl1;
    {
        size_t b0 = (size_t)(w*2)*64 + lane;
        cbh0 = W1H[b0]; cbh1 = W1H[b0 + 64];
        cbl0 = W1L[b0]; cbl1 = W1L[b0 + 64];
    }

    // ================= GEMM1: 25 k-steps, NO barriers =================
    #pragma unroll
    for (int ks = 0; ks < NKS1; ++ks) {
        // convert arrived A to bf16 hi
        short8v ah0 = cvt8(a00, a01);
        short8v ah1 = cvt8(a10, a11);

        // prefetch A for ks+1 (WAR on a-regs after cvt)
        if (ks + 1 < NKS1) {
            const int c = (ks + 1) * 16 + hs * 8;
            const float* p0 = (c < HID) ? h0 : x0;
            const float* p1 = (c < HID) ? h1 : x1;
            a00 = *(const float4*)(p0 + c);  a01 = *(const float4*)(p0 + c + 4);
            a10 = *(const float4*)(p1 + c);  a11 = *(const float4*)(p1 + c + 4);
        }
        // prefetch B for ks+1 (dummy ks=0 on last)
        short8v nbh0, nbh1, nbl0, nbl1;
        {
            size_t nb_ = (size_t)(((ks + 1 < NKS1 ? ks + 1 : 0)) * 8 + w*2)*64 + lane;
            nbh0 = W1H[nb_]; nbh1 = W1H[nb_ + 64];
            nbl0 = W1L[nb_]; nbl1 = W1L[nb_ + 64];
        }

        acc00 = __builtin_amdgcn_mfma_f32_32x32x16_bf16(ah0, cbh0, acc00, 0,0,0);
        acc00 = __builtin_amdgcn_mfma_f32_32x32x16_bf16(ah0, cbl0, acc00, 0,0,0);
        acc01 = __builtin_amdgcn_mfma_f32_32x32x16_bf16(ah0, cbh1, acc01, 0,0,0);
        acc01 = __builtin_amdgcn_mfma_f32_32x32x16_bf16(ah0, cbl1, acc01, 0,0,0);
        acc10 = __builtin_amdgcn_mfma_f32_32x32x16_bf16(ah1, cbh0, acc10, 0,0,0);
        acc10 = __builtin_amdgcn_mfma_f32_32x32x16_bf16(ah1, cbl0, acc10, 0,0,0);
        acc11 = __builtin_amdgcn_mfma_f32_32x32x16_bf16(ah1, cbh1, acc11, 0,0,0);
        acc11 = __builtin_amdgcn_mfma_f32_32x32x16_bf16(ah1, cbl1, acc11, 0,0,0);

        cbh0 = nbh0; cbh1 = nbh1; cbl0 = nbl0; cbl1 = nbl1;
    }

    // ---- epilogue1: bias + relu + bf16 (hi only) -> F1h (XOR-swizzled) ----
    // C/D layout: col = lane&31, row = (r&3) + 8*(r>>2) + 4*(lane>>5)
    const float b1c0 = b1[w*64 + l31];
    const float b1c1 = b1[w*64 + 32 + l31];
#define EPI1(ACC, MI, NI) do {                                            \
        int gcol = w*64 + (NI)*32 + l31;                                  \
        float bb = (NI) ? b1c1 : b1c0;                                    \
        _Pragma("unroll")                                                 \
        for (int r = 0; r < 16; ++r) {                                    \
            int grow = (MI)*32 + (r & 3) + 8*(r >> 2) + 4*hs;             \
            float v = fmaxf(ACC[r] + bb, 0.f);                            \
            int phys = grow*256 + (((gcol >> 3) ^ (grow & 31)) << 3) + (gcol & 7); \
            F1h[phys] = f2bf(v);                                          \
        } } while (0)
    EPI1(acc00, 0, 0); EPI1(acc01, 0, 1); EPI1(acc10, 1, 0); EPI1(acc11, 1, 1);
#undef EPI1
    __syncthreads();

    // ================= GEMM2: feat2 = relu(feat1 @ W2 + b2) =================
    // A = bf16(feat1) hi-only; B = W2 hi+lo (2 MFMAs per K-step).
    f32x16 acc2;
    #pragma unroll
    for (int r = 0; r < 16; ++r) acc2[r] = 0.f;
    const int m2   = w >> 1;      // node-row half
    const int nt2  = w & 1;       // col half
    const int arow = m2*32 + l31;

    const short8v* W2H = (const short8v*)w2h;
    const short8v* W2L = (const short8v*)w2l;
    short8v bhc = W2H[(size_t)nt2*64 + lane];
    short8v blc = W2L[(size_t)nt2*64 + lane];
    #pragma unroll
    for (int ks = 0; ks < NKS2; ++ks) {
        short8v bhn = bhc, bln = blc;
        if (ks + 1 < NKS2) {
            size_t nbase = (size_t)((ks + 1)*2 + nt2)*64 + lane;
            bhn = W2H[nbase];
            bln = W2L[nbase];
        }
        int blk  = (ks*2 + hs) ^ (arow & 31);
        short8v ah2 = *(const short8v*)&F1h[arow*256 + blk*8];
        acc2 = __builtin_amdgcn_mfma_f32_32x32x16_bf16(ah2, bhc, acc2, 0,0,0);
        acc2 = __builtin_amdgcn_mfma_f32_32x32x16_bf16(ah2, blc, acc2, 0,0,0);
        bhc = bhn; blc = bln;
    }
    __syncthreads();   // all F1 reads done; s2p/srow may now overwrite LDS

    // ---- epilogue2: s_n = relu(feat2 + b2) . Wout, 32-col shfl reduce ----
    {
        const int   col2 = nt2*32 + l31;
        const float b2c  = b2[col2];
        const float woc  = Wout[col2];
        #pragma unroll
        for (int r = 0; r < 16; ++r) {
            float v = fmaxf(acc2[r] + b2c, 0.f) * woc;
            v += __shfl_xor(v, 1);
            v += __shfl_xor(v, 2);
            v += __shfl_xor(v, 4);
            v += __shfl_xor(v, 8);
            v += __shfl_xor(v, 16);
            if (l31 == 0) {
                int grow = m2*32 + (r & 3) + 8*(r >> 2) + 4*hs;
                s2p[nt2*64 + grow] = v;   // [colhalf][row]
            }
        }
    }
    __syncthreads();
    if (t < 64) srow[t] = s2p[t] + s2p[64 + t];
    __syncthreads();

    // ---- segmented sum over sorted batch, one atomic per run ----
    if (t < 64) {
        int node = n0 + t;
        int b = (node < N) ? batch[node] : -1;
        int pb = (t == 0) ? -2 : ((node - 1 < N) ? batch[node - 1] : -1);
        if (b >= 0 && b != pb) {
            float acc = 0.f;
            int j = t;
            while (j < 64 && (n0 + j) < N && batch[n0 + j] == b) { acc += srow[j]; ++j; }
            atomicAdd(&gf1d[b], acc);
        }
    }
}

__global__ void final_sigmoid(const float* __restrict__ gf1d, const float* __restrict__ bout,
                              float* __restrict__ out, int G)
{
    int g = blockIdx.x * 256 + threadIdx.x;
    if (g < G) out[g] = 1.f / (1.f + expf(-(gf1d[g] + bout[0])));
}

extern "C" void kernel_launch(void* const* d_in, const int* in_sizes, int n_in,
                              void* d_out, int out_size, void* d_ws, size_t ws_size,
                              hipStream_t stream)
{
    const float* h    = (const float*)d_in[0];
    const float* x    = (const float*)d_in[1];
    const int*   batch= (const int*)d_in[2];
    const float* W1   = (const float*)d_in[3];
    const float* b1   = (const float*)d_in[4];
    const float* W2   = (const float*)d_in[5];
    const float* b2   = (const float*)d_in[6];
    const float* Wout = (const float*)d_in[7];
    const float* bout = (const float*)d_in[8];
    float* out = (float*)d_out;

    const int N = in_sizes[2];
    const int G = out_size;

    // workspace layout (~483 KB total)
    char* ws = (char*)d_ws;
    float* gf1d = (float*)ws;                                  //   8,192 B
    unsigned short* w1h = (unsigned short*)(ws + 8192);        // 204,800 B
    unsigned short* w1l = w1h + (size_t)W1P_SH8 * 8;           // 204,800 B
    unsigned short* w2h = w1l + (size_t)W1P_SH8 * 8;           //  32,768 B
    unsigned short* w2l = w2h + (size_t)W2P_SH8 * 8;           //  32,768 B

    hipMemsetAsync(gf1d, 0, 8192, stream);
    pack_weights<<<(W1P_SH8 + W2P_SH8 + 255) / 256, 256, 0, stream>>>(W1, W2, w1h, w1l, w2h, w2l);
    fused_readout<<<(N + BM - 1) / BM, 256, 0, stream>>>(h, x, batch, w1h, w1l, w2h, w2l,
                                                         b1, b2, Wout, gf1d, N);
    final_sigmoid<<<(G + 255) / 256, 256, 0, stream>>>(gf1d, bout, out, G);
}

// Round 8
// 206.639 us; speedup vs baseline: 1.3281x; 1.3281x over previous
//
#include <hip/hip_runtime.h>
#include <hip/hip_bf16.h>
#include <math.h>

// Fused GNN readout via bf16-split MFMA (v_mfma_f32_32x32x16_bf16):
//   feat1 = relu(concat(h,x) @ W1 + b1)   [N,256]  GEMM1: K=400(pad 448), A=bf16 hi, B=hi+lo
//   feat2 = relu(feat1 @ W2 + b2)         [N,64]   GEMM2: K=256, A=bf16 hi, B=hi+lo
//   s_n   = feat2 . Wout ; out = sigmoid(segment_sum(s_n) + bout)
// R8: counted-vmcnt pipeline (m201/T3/T4 pattern, plain HIP):
//   - A fp32 via global_load_lds into a 3-buffer LDS ring, issued 2 chunks
//     ahead; raw s_barrier + asm s_waitcnt vmcnt(12/8) — NEVER drained to 0
//     inside the loop. In-order vmem completion makes the count safe.
//   - B register prefetch depth 2 (covers L2 latency).
//   - s_setprio(1) around each 8-MFMA cluster (T5).

typedef __attribute__((ext_vector_type(8)))  short short8v;
typedef __attribute__((ext_vector_type(16))) float f32x16;

#define G_NUM 2048
#define HID 200
#define EMB 200
#define DIN 400
#define NH1 256
#define NH2 64
#define BM  64
#define NKS1 28        // bf16 K-steps (of 16) for GEMM1, K padded 400->448
#define NCH  7         // 7 chunks of 64 fp32 cols
#define NKS2 16        // K-steps for GEMM2 (K=256)

#define W1P_SH8 (NKS1*8*64)   // 14336 fragments (16B each) per plane
#define W2P_SH8 (NKS2*2*64)   // 2048

__device__ __forceinline__ unsigned short f2bf(float f) {
    union { float f; unsigned u; } v; v.f = f;
    unsigned r = v.u + 0x7fffu + ((v.u >> 16) & 1u);   // RNE
    return (unsigned short)(r >> 16);
}
__device__ __forceinline__ float bf2f(unsigned short b) {
    union { unsigned u; float f; } v; v.u = ((unsigned)b) << 16;
    return v.f;
}
// 8 fp32 -> 8 bf16 (RNE) via packed converts
__device__ __forceinline__ short8v cvt8(float4 a, float4 b) {
    union { __hip_bfloat162 q[4]; short8v s8; } u;
    u.q[0] = __float22bfloat162_rn(make_float2(a.x, a.y));
    u.q[1] = __float22bfloat162_rn(make_float2(a.z, a.w));
    u.q[2] = __float22bfloat162_rn(make_float2(b.x, b.y));
    u.q[3] = __float22bfloat162_rn(make_float2(b.z, b.w));
    return u.s8;
}

// Pre-pack W1/W2 into MFMA-fragment order, hi/lo bf16 planes.
// Fragment (ks, ntile, lane) holds 8 bf16: B[k0+j][col], k0=ks*16+(lane>>5)*8,
// col=ntile*32+(lane&31). Contiguous-8 k in BOTH A and B => any consistent
// hw k-permutation cancels in the dot product.
__global__ void pack_weights(const float* __restrict__ W1, const float* __restrict__ W2,
                             unsigned short* __restrict__ w1h, unsigned short* __restrict__ w1l,
                             unsigned short* __restrict__ w2h, unsigned short* __restrict__ w2l)
{
    int idx = blockIdx.x * 256 + threadIdx.x;
    if (idx < W1P_SH8) {
        int l  = idx & 63;
        int nt = (idx >> 6) & 7;
        int ks = idx >> 9;
        int col = nt * 32 + (l & 31);
        int k0  = ks * 16 + (l >> 5) * 8;
        short8v H, L;
        #pragma unroll
        for (int j = 0; j < 8; ++j) {
            int k = k0 + j;
            float v = (k < DIN) ? W1[(size_t)k * NH1 + col] : 0.f;
            unsigned short hh = f2bf(v);
            H[j] = (short)hh;
            L[j] = (short)f2bf(v - bf2f(hh));
        }
        ((short8v*)w1h)[idx] = H;
        ((short8v*)w1l)[idx] = L;
    } else if (idx < W1P_SH8 + W2P_SH8) {
        int i2 = idx - W1P_SH8;
        int l  = i2 & 63;
        int nt = (i2 >> 6) & 1;
        int ks = i2 >> 7;
        int col = nt * 32 + (l & 31);
        int k0  = ks * 16 + (l >> 5) * 8;
        short8v H, L;
        #pragma unroll
        for (int j = 0; j < 8; ++j) {
            float v = W2[(size_t)(k0 + j) * NH2 + col];
            unsigned short hh = f2bf(v);
            H[j] = (short)hh;
            L[j] = (short)f2bf(v - bf2f(hh));
        }
        ((short8v*)w2h)[i2] = H;
        ((short8v*)w2l)[i2] = L;
    }
}

__launch_bounds__(256, 3)
__global__ void fused_readout(const float* __restrict__ h, const float* __restrict__ x,
                              const int* __restrict__ batch,
                              const unsigned short* __restrict__ w1h, const unsigned short* __restrict__ w1l,
                              const unsigned short* __restrict__ w2h, const unsigned short* __restrict__ w2l,
                              const float* __restrict__ b1, const float* __restrict__ b2,
                              const float* __restrict__ Wout, const float* __restrict__ zbuf,
                              float* __restrict__ gf1d, int N)
{
    // 49152 B LDS, time-multiplexed:
    //   [GEMM1] A fp32 ring: 3 bufs x [64 rows][64 fp32] = 49152 B
    //           (row stride 256 B; 16B-granule XOR swizzle c16 ^= row&15 applied
    //            on the GLOBAL SOURCE; LDS dest linear for global_load_lds)
    //   [GEMM2] F1h [64][256] bf16 = 32768 B (overlaps ring bufs 0-1)
    //   [pool ] s2p[2][64] f32 at 0, srow[64] f32 at byte 512
    __shared__ __align__(16) char lds[49152];
    unsigned short* F1h = (unsigned short*)lds;
    float* s2p  = (float*)lds;          // 128 floats
    float* srow = (float*)(lds + 512);  // 64 floats

    const int t    = threadIdx.x;
    const int lane = t & 63;
    const int w    = t >> 6;
    const int n0   = blockIdx.x * BM;
    const int l31  = lane & 31;
    const int hs   = lane >> 5;         // k-half select

    const short8v* W1H = (const short8v*)w1h;
    const short8v* W1L = (const short8v*)w1l;

    f32x16 acc00, acc01, acc10, acc11;
    #pragma unroll
    for (int r = 0; r < 16; ++r) { acc00[r] = 0.f; acc01[r] = 0.f; acc10[r] = 0.f; acc11[r] = 0.f; }

    // ---- helpers ----
    // issue 4 global_load_lds covering this wave's 16 rows of chunk CH into ring buffer BUF
    // dest: linear  BUF*16384 + brow*256 + lane*16
    // src : per-lane, pre-swizzled col16 = (lane&15) ^ (row&15); OOB -> zbuf
    #define AISSUE(CH, BUF) do {                                               \
        _Pragma("unroll")                                                      \
        for (int ii = 0; ii < 4; ++ii) {                                       \
            int brow = w*16 + ii*4;                                            \
            int row  = brow + (lane >> 4);                                     \
            int node = n0 + row;                                               \
            int colf = (CH)*64 + (((lane & 15) ^ (row & 15)) << 2);            \
            const float* src;                                                  \
            if (node >= N || colf >= DIN) src = zbuf + (lane & 15)*4;          \
            else if (colf < HID)          src = h + (size_t)node*HID + colf;   \
            else                          src = x + (size_t)node*EMB + (colf - HID); \
            __builtin_amdgcn_global_load_lds(                                  \
                (const __attribute__((address_space(1))) unsigned*)src,        \
                (__attribute__((address_space(3))) unsigned*)(lds + (BUF)*16384 + brow*256 + lane*16), \
                16, 0, 0);                                                     \
        } } while (0)

    // A fragment: row ROW, logical col16 pair {S*4+hs*2, +1} of ring buffer (byte base HB)
    #define AFRAG(HB, S, ROW)                                                  \
        cvt8(*(const float4*)(lds + (HB) + (ROW)*256 + ((((S)*4 + hs*2)     ^ ((ROW) & 15)) << 4)), \
             *(const float4*)(lds + (HB) + (ROW)*256 + ((((S)*4 + hs*2 + 1) ^ ((ROW) & 15)) << 4)))

    // load one k-step's 4 B fragments into named regs
    #define BLOAD(KS, H0, H1, L0, L1) do {                                     \
        size_t nb_ = ((size_t)((KS)*8 + w*2))*64 + lane;                       \
        H0 = W1H[nb_]; H1 = W1H[nb_ + 64];                                     \
        L0 = W1L[nb_]; L1 = W1L[nb_ + 64]; } while (0)

    // ---- prologue: A chunks 0,1 in flight; B ksteps 0,1 in regs-in-flight ----
    AISSUE(0, 0);
    AISSUE(1, 1);
    short8v c0h0, c0h1, c0l0, c0l1;    // B(ks)   — consumed this k-step
    short8v c1h0, c1h1, c1l0, c1l1;    // B(ks+1)
    BLOAD(0, c0h0, c0h1, c0l0, c0l1);
    BLOAD(1, c1h0, c1h1, c1l0, c1l1);

    // ================= GEMM1: 7 chunks x 4 k-steps, counted-vmcnt pipeline =================
    #pragma unroll
    for (int c = 0; c < NCH; ++c) {
        // need ring buf c ready: per-wave outstanding newer than A(c) is
        // A(c+1):4 + B:8 = 12 (c<6) or B:8 = 8 (c==6). In-order completion
        // makes vmcnt(N) guarantee the older A(c) loads are done.
        if (c < 6) { asm volatile("s_waitcnt vmcnt(12)" ::: "memory"); }
        else       { asm volatile("s_waitcnt vmcnt(8)"  ::: "memory"); }
        __builtin_amdgcn_s_barrier();   // all waves' A(c) complete; buf (c+2)%3 free
        if (c + 2 < NCH) AISSUE(c + 2, (c + 2) % 3);

        const int hb = (c % 3) * 16384;
        #pragma unroll
        for (int s = 0; s < 4; ++s) {
            const int ks = c * 4 + s;
            // prefetch B(ks+2) (depth 2; dummy ks=0 at tail)
            short8v n2h0, n2h1, n2l0, n2l1;
            BLOAD((ks + 2 < NKS1) ? ks + 2 : 0, n2h0, n2h1, n2l0, n2l1);
            // A fragments (LDS ring) + convert
            short8v ah0 = AFRAG(hb, s, l31);
            short8v ah1 = AFRAG(hb, s, 32 + l31);
            __builtin_amdgcn_s_setprio(1);
            acc00 = __builtin_amdgcn_mfma_f32_32x32x16_bf16(ah0, c0h0, acc00, 0,0,0);
            acc00 = __builtin_amdgcn_mfma_f32_32x32x16_bf16(ah0, c0l0, acc00, 0,0,0);
            acc01 = __builtin_amdgcn_mfma_f32_32x32x16_bf16(ah0, c0h1, acc01, 0,0,0);
            acc01 = __builtin_amdgcn_mfma_f32_32x32x16_bf16(ah0, c0l1, acc01, 0,0,0);
            acc10 = __builtin_amdgcn_mfma_f32_32x32x16_bf16(ah1, c0h0, acc10, 0,0,0);
            acc10 = __builtin_amdgcn_mfma_f32_32x32x16_bf16(ah1, c0l0, acc10, 0,0,0);
            acc11 = __builtin_amdgcn_mfma_f32_32x32x16_bf16(ah1, c0h1, acc11, 0,0,0);
            acc11 = __builtin_amdgcn_mfma_f32_32x32x16_bf16(ah1, c0l1, acc11, 0,0,0);
            __builtin_amdgcn_s_setprio(0);
            // rotate B pipeline
            c0h0 = c1h0; c0h1 = c1h1; c0l0 = c1l0; c0l1 = c1l1;
            c1h0 = n2h0; c1h1 = n2h1; c1l0 = n2l0; c1l1 = n2l1;
        }
    }
    #undef BLOAD
    #undef AFRAG
    #undef AISSUE

    __syncthreads();   // all ring reads done; F1h may overwrite bufs 0-1

    // ---- epilogue1: bias + relu + bf16 (hi only) -> F1h (XOR-swizzled) ----
    // C/D layout: col = lane&31, row = (r&3) + 8*(r>>2) + 4*(lane>>5)
    const float b1c0 = b1[w*64 + l31];
    const float b1c1 = b1[w*64 + 32 + l31];
#define EPI1(ACC, MI, NI) do {                                            \
        int gcol = w*64 + (NI)*32 + l31;                                  \
        float bb = (NI) ? b1c1 : b1c0;                                    \
        _Pragma("unroll")                                                 \
        for (int r = 0; r < 16; ++r) {                                    \
            int grow = (MI)*32 + (r & 3) + 8*(r >> 2) + 4*hs;             \
            float v = fmaxf(ACC[r] + bb, 0.f);                            \
            int phys = grow*256 + (((gcol >> 3) ^ (grow & 31)) << 3) + (gcol & 7); \
            F1h[phys] = f2bf(v);                                          \
        } } while (0)
    EPI1(acc00, 0, 0); EPI1(acc01, 0, 1); EPI1(acc10, 1, 0); EPI1(acc11, 1, 1);
#undef EPI1
    __syncthreads();

    // ================= GEMM2: feat2 = relu(feat1 @ W2 + b2) =================
    // A = bf16(feat1) hi-only; B = W2 hi+lo (2 MFMAs per K-step).
    f32x16 acc2;
    #pragma unroll
    for (int r = 0; r < 16; ++r) acc2[r] = 0.f;
    const int m2   = w >> 1;      // node-row half
    const int nt2  = w & 1;       // col half
    const int arow = m2*32 + l31;

    const short8v* W2H = (const short8v*)w2h;
    const short8v* W2L = (const short8v*)w2l;
    short8v bhc = W2H[(size_t)nt2*64 + lane];
    short8v blc = W2L[(size_t)nt2*64 + lane];
    #pragma unroll
    for (int ks = 0; ks < NKS2; ++ks) {
        short8v bhn = bhc, bln = blc;
        if (ks + 1 < NKS2) {
            size_t nbase = (size_t)((ks + 1)*2 + nt2)*64 + lane;
            bhn = W2H[nbase];
            bln = W2L[nbase];
        }
        int blk  = (ks*2 + hs) ^ (arow & 31);
        short8v ah2 = *(const short8v*)&F1h[arow*256 + blk*8];
        acc2 = __builtin_amdgcn_mfma_f32_32x32x16_bf16(ah2, bhc, acc2, 0,0,0);
        acc2 = __builtin_amdgcn_mfma_f32_32x32x16_bf16(ah2, blc, acc2, 0,0,0);
        bhc = bhn; blc = bln;
    }
    __syncthreads();   // all F1 reads done; s2p/srow may now overwrite LDS

    // ---- epilogue2: s_n = relu(feat2 + b2) . Wout, 32-col shfl reduce ----
    {
        const int   col2 = nt2*32 + l31;
        const float b2c  = b2[col2];
        const float woc  = Wout[col2];
        #pragma unroll
        for (int r = 0; r < 16; ++r) {
            float v = fmaxf(acc2[r] + b2c, 0.f) * woc;
            v += __shfl_xor(v, 1);
            v += __shfl_xor(v, 2);
            v += __shfl_xor(v, 4);
            v += __shfl_xor(v, 8);
            v += __shfl_xor(v, 16);
            if (l31 == 0) {
                int grow = m2*32 + (r & 3) + 8*(r >> 2) + 4*hs;
                s2p[nt2*64 + grow] = v;   // [colhalf][row]
            }
        }
    }
    __syncthreads();
    if (t < 64) srow[t] = s2p[t] + s2p[64 + t];
    __syncthreads();

    // ---- segmented sum over sorted batch, one atomic per run ----
    if (t < 64) {
        int node = n0 + t;
        int b = (node < N) ? batch[node] : -1;
        int pb = (t == 0) ? -2 : ((node - 1 < N) ? batch[node - 1] : -1);
        if (b >= 0 && b != pb) {
            float acc = 0.f;
            int j = t;
            while (j < 64 && (n0 + j) < N && batch[n0 + j] == b) { acc += srow[j]; ++j; }
            atomicAdd(&gf1d[b], acc);
        }
    }
}

__global__ void final_sigmoid(const float* __restrict__ gf1d, const float* __restrict__ bout,
                              float* __restrict__ out, int G)
{
    int g = blockIdx.x * 256 + threadIdx.x;
    if (g < G) out[g] = 1.f / (1.f + expf(-(gf1d[g] + bout[0])));
}

extern "C" void kernel_launch(void* const* d_in, const int* in_sizes, int n_in,
                              void* d_out, int out_size, void* d_ws, size_t ws_size,
                              hipStream_t stream)
{
    const float* h    = (const float*)d_in[0];
    const float* x    = (const float*)d_in[1];
    const int*   batch= (const int*)d_in[2];
    const float* W1   = (const float*)d_in[3];
    const float* b1   = (const float*)d_in[4];
    const float* W2   = (const float*)d_in[5];
    const float* b2   = (const float*)d_in[6];
    const float* Wout = (const float*)d_in[7];
    const float* bout = (const float*)d_in[8];
    float* out = (float*)d_out;

    const int N = in_sizes[2];
    const int G = out_size;

    // workspace layout (~533 KB total)
    char* ws = (char*)d_ws;
    float* gf1d = (float*)ws;                                  //   8,192 B
    float* zbuf = (float*)(ws + 8192);                         //   1,024 B (zeros)
    unsigned short* w1h = (unsigned short*)(ws + 9216);        // 229,376 B
    unsigned short* w1l = w1h + (size_t)W1P_SH8 * 8;           // 229,376 B
    unsigned short* w2h = w1l + (size_t)W1P_SH8 * 8;           //  32,768 B
    unsigned short* w2l = w2h + (size_t)W2P_SH8 * 8;           //  32,768 B

    hipMemsetAsync(gf1d, 0, 9216, stream);   // gf accumulators + zero buffer
    pack_weights<<<(W1P_SH8 + W2P_SH8 + 255) / 256, 256, 0, stream>>>(W1, W2, w1h, w1l, w2h, w2l);
    fused_readout<<<(N + BM - 1) / BM, 256, 0, stream>>>(h, x, batch, w1h, w1l, w2h, w2l,
                                                         b1, b2, Wout, zbuf, gf1d, N);
    final_sigmoid<<<(G + 255) / 256, 256, 0, stream>>>(gf1d, bout, out, G);
}